// Round 23
// baseline (119.333 us; speedup 1.0000x reference)
//
#include <hip/hip_runtime.h>
#include <math.h>

static constexpr int FI = 128;  // input features
static constexpr int FH = 16;   // hidden
static constexpr int FO = 8;    // classes

static constexpr int BIN_SHIFT = 8;        // 256 nodes per bin
static constexpr int BIN_NODES = 256;
static constexpr int MAX_BINS  = 512;      // supports N <= 131072 (row fits 17 bits)
static constexpr int CAPB      = 9728;     // per-bin capacity (mean 8192 +7sigma +768 pad)
static constexpr int SCHUNK    = 8192;     // edges per scatter chunk
static constexpr int SThreads  = 1024;     // scatter/gemm block size (16 waves, 2 blocks/CU)

__device__ __forceinline__ unsigned short f2bf(float x) {
    unsigned u = __float_as_uint(x);
    u += 0x7FFFu + ((u >> 16) & 1u);       // round-to-nearest-even
    return (unsigned short)(u >> 16);
}
__device__ __forceinline__ float bflo(unsigned u) { return __uint_as_float(u << 16); }
__device__ __forceinline__ float bfhi(unsigned u) { return __uint_as_float(u & 0xFFFF0000u); }

// ---- fused: scatter chunks + unscaled gemm1, 1:1 interleaved block mapping ----
// 1024-thread blocks, 46 KB LDS -> 2 blocks/CU = 32 waves/CU (full wave slots).
struct SMemScatter {
    int lcnt[MAX_BINS];
    int lstart[MAX_BINS];
    int gbase[MAX_BINS];
    int wsum[8];
    unsigned int  staged[SCHUNK];          // 32 KB
    unsigned char sbin[SCHUNK];            // 8 KB
};
struct SMemGemm { float sw[FI * FH]; };    // 8 KB
union SMemU { SMemScatter s; SMemGemm g; };

__launch_bounds__(SThreads, 8)             // 8 waves/EU = 32 waves/CU (2 blocks)
__global__ void k_scatter_gemm(const int* __restrict__ row, const int* __restrict__ col,
                               int* __restrict__ binCursor, unsigned int* __restrict__ binned,
                               const float* __restrict__ x, const float* __restrict__ W1,
                               unsigned short* __restrict__ xw1, int E, int nchunks, int N) {
    __shared__ SMemU sm;
    int t = threadIdx.x;
    int i = (int)blockIdx.x;

    bool isScatter = ((i & 1) == 0) && ((i >> 1) < nchunks);

    if (!isScatter) {
        // ---------------- gemm1 (unscaled): 256 nodes per block ----------------
        int nsc  = (i + 1) >> 1; if (nsc > nchunks) nsc = nchunks;   // scatter blocks before i
        int tile = i - nsc;
        for (int k = t; k < FI * FH; k += SThreads) sm.g.sw[k] = W1[k];
        __syncthreads();
        int nl = t >> 2;            // 0..255 local node
        int f  = (t & 3) * 4;       // 0,4,8,12
        int n  = tile * 256 + nl;
        if (n >= N) return;
        const float4* xr = (const float4*)(x + (size_t)n * FI);
        float a0 = 0.f, a1 = 0.f, a2 = 0.f, a3 = 0.f;
        #pragma unroll 8
        for (int kq = 0; kq < FI / 4; ++kq) {
            float4 xv = xr[kq];
            float4 w0 = *(const float4*)&sm.g.sw[(kq * 4 + 0) * FH + f];
            float4 w1 = *(const float4*)&sm.g.sw[(kq * 4 + 1) * FH + f];
            float4 w2 = *(const float4*)&sm.g.sw[(kq * 4 + 2) * FH + f];
            float4 w3 = *(const float4*)&sm.g.sw[(kq * 4 + 3) * FH + f];
            a0 = fmaf(xv.x, w0.x, a0); a1 = fmaf(xv.x, w0.y, a1);
            a2 = fmaf(xv.x, w0.z, a2); a3 = fmaf(xv.x, w0.w, a3);
            a0 = fmaf(xv.y, w1.x, a0); a1 = fmaf(xv.y, w1.y, a1);
            a2 = fmaf(xv.y, w1.z, a2); a3 = fmaf(xv.y, w1.w, a3);
            a0 = fmaf(xv.z, w2.x, a0); a1 = fmaf(xv.z, w2.y, a1);
            a2 = fmaf(xv.z, w2.z, a2); a3 = fmaf(xv.z, w2.w, a3);
            a0 = fmaf(xv.w, w3.x, a0); a1 = fmaf(xv.w, w3.y, a1);
            a2 = fmaf(xv.w, w3.z, a2); a3 = fmaf(xv.w, w3.w, a3);
        }
        unsigned p0 = (unsigned)f2bf(a0) | ((unsigned)f2bf(a1) << 16);
        unsigned p1 = (unsigned)f2bf(a2) | ((unsigned)f2bf(a3) << 16);
        *(uint2*)(xw1 + (size_t)n * FH + f) = make_uint2(p0, p1);
        return;
    }

    // ---------------- scatter chunk ----------------
    int chunk = i >> 1;
    int base = chunk * SCHUNK;
    int end  = base + SCHUNK; if (end > E) end = E;
    int m = end - base;
    if (t < MAX_BINS) sm.s.lcnt[t] = 0;
    __syncthreads();

    // pass 1: histogram; col AND arrival index staged in registers
    int nv = m >> 2;
    const int4* c4 = (const int4*)(col + base);
    int4 creg[2];
    unsigned short a16[8];
    #pragma unroll
    for (int j = 0; j < 2; ++j) {
        int k = t + j * SThreads;
        if (k < nv) {
            creg[j] = c4[k];
            a16[j*4+0] = (unsigned short)atomicAdd(&sm.s.lcnt[creg[j].x >> BIN_SHIFT], 1);
            a16[j*4+1] = (unsigned short)atomicAdd(&sm.s.lcnt[creg[j].y >> BIN_SHIFT], 1);
            a16[j*4+2] = (unsigned short)atomicAdd(&sm.s.lcnt[creg[j].z >> BIN_SHIFT], 1);
            a16[j*4+3] = (unsigned short)atomicAdd(&sm.s.lcnt[creg[j].w >> BIN_SHIFT], 1);
        }
    }
    int tailIdx = base + (nv << 2) + t;     // at most 3 tail edges total
    int tailCol = 0, tailA = -1;
    if (tailIdx < end) {
        tailCol = col[tailIdx];
        tailA = atomicAdd(&sm.s.lcnt[tailCol >> BIN_SHIFT], 1);
    }
    __syncthreads();

    // wave-shuffle scan over 512 bins (first 8 waves)
    int inc = 0, v = 0;
    if (t < MAX_BINS) {
        v = sm.s.lcnt[t];
        inc = v;
        #pragma unroll
        for (int d = 1; d < 64; d <<= 1) {
            int u = __shfl_up(inc, d, 64);
            if ((t & 63) >= d) inc += u;
        }
        if ((t & 63) == 63) sm.s.wsum[t >> 6] = inc;
    }
    __syncthreads();
    if (t < 8) {
        int w = sm.s.wsum[t];
        #pragma unroll
        for (int d = 1; d < 8; d <<= 1) {
            int u = __shfl_up(w, d, 8);
            if (t >= d) w += u;
        }
        sm.s.wsum[t] = w;
    }
    __syncthreads();
    if (t < MAX_BINS) {
        int waveoff = (t >= 64) ? sm.s.wsum[(t >> 6) - 1] : 0;
        sm.s.lstart[t] = waveoff + inc - v;
        sm.s.gbase[t]  = v ? atomicAdd(&binCursor[t], v) : 0;   // offset within bin region
    }
    __syncthreads();

    // pass 2: place into LDS staging (atomic-free: lstart[bin] + arrival)
    const int4* r4 = (const int4*)(row + base);
    #pragma unroll
    for (int j = 0; j < 2; ++j) {
        int k = t + j * SThreads;
        if (k < nv) {
            int4 r = r4[k];
            int cc[4] = {creg[j].x, creg[j].y, creg[j].z, creg[j].w};
            int rr[4] = {r.x, r.y, r.z, r.w};
            #pragma unroll
            for (int jj = 0; jj < 4; ++jj) {
                int b = cc[jj] >> BIN_SHIFT;
                int pos = sm.s.lstart[b] + a16[j*4+jj];
                sm.s.staged[pos] = (unsigned)rr[jj] | ((unsigned)(cc[jj] & (BIN_NODES - 1)) << 17)
                                 | ((unsigned)(b >> 8) << 25);
                sm.s.sbin[pos] = (unsigned char)b;
            }
        }
    }
    if (tailA >= 0) {
        int b = tailCol >> BIN_SHIFT;
        int pos = sm.s.lstart[b] + tailA;
        sm.s.staged[pos] = (unsigned)row[tailIdx] | ((unsigned)(tailCol & (BIN_NODES - 1)) << 17)
                         | ((unsigned)(b >> 8) << 25);
        sm.s.sbin[pos] = (unsigned char)b;
    }
    __syncthreads();

    // pass 3: coalesced flush (consecutive i in a run -> consecutive global addrs)
    for (int k = t; k < m; k += SThreads) {
        unsigned sv = sm.s.staged[k];
        int b = (int)sm.s.sbin[k] | (int)((sv >> 25) & 1u) << 8;
        int off = sm.s.gbase[b] + (k - sm.s.lstart[b]);
        if (off < CAPB) binned[b * CAPB + off] = sv & 0x1FFFFFFu;
    }
}

// ---- per-bin CSR build: arrival-idx hist -> PADDED scan (4-aligned runs) ----
__launch_bounds__(BIN_NODES)
__global__ void k_refine(const int* __restrict__ binCursor, const unsigned int* __restrict__ binned,
                         int* __restrict__ srow, int* __restrict__ starts, int* __restrict__ ends,
                         float* __restrict__ dis, unsigned short* __restrict__ xw1, int N) {
    __shared__ unsigned char arr[CAPB];      // 9.5 KB arrival index (deg < 256)
    __shared__ int cnt[BIN_NODES];           // histogram -> padded exclusive offsets
    __shared__ int wsum[4];
    int t = threadIdx.x;
    int b = blockIdx.x;
    int s = b * CAPB;
    int m = binCursor[b];                    // count of edges in bin
    if (m > CAPB - 768) m = CAPB - 768;      // leave room for per-node pad
    cnt[t] = 0;
    __syncthreads();

    // pass A: histogram with arrival index (single atomic per edge)
    int mm = m & ~3;
    for (int i0 = t * 4; i0 < mm; i0 += BIN_NODES * 4) {
        uint4 v = *(const uint4*)(binned + s + i0);
        arr[i0 + 0] = (unsigned char)atomicAdd(&cnt[v.x >> 17], 1);
        arr[i0 + 1] = (unsigned char)atomicAdd(&cnt[v.y >> 17], 1);
        arr[i0 + 2] = (unsigned char)atomicAdd(&cnt[v.z >> 17], 1);
        arr[i0 + 3] = (unsigned char)atomicAdd(&cnt[v.w >> 17], 1);
    }
    for (int i = mm + t; i < m; i += BIN_NODES)
        arr[i] = (unsigned char)atomicAdd(&cnt[binned[s + i] >> 17], 1);
    __syncthreads();

    // wave-shuffle inclusive scan of 256 PADDED degrees (runs 4-int aligned)
    int deg  = cnt[t];
    int pdeg = (deg + 3) & ~3;
    int inc = pdeg;
    #pragma unroll
    for (int d = 1; d < 64; d <<= 1) {
        int u = __shfl_up(inc, d, 64);
        if ((t & 63) >= d) inc += u;
    }
    if ((t & 63) == 63) wsum[t >> 6] = inc;
    __syncthreads();
    if (t < 4) {
        int w = wsum[t];
        #pragma unroll
        for (int d = 1; d < 4; d <<= 1) {
            int u = __shfl_up(w, d, 4);
            if (t >= d) w += u;
        }
        wsum[t] = w;
    }
    __syncthreads();
    int waveoff = (t >= 64) ? wsum[(t >> 6) - 1] : 0;
    int pexcl = waveoff + inc - pdeg;

    int n = b * BIN_NODES + t;
    float dv = rsqrtf((float)(deg + 1));     // +1 self loop
    if (n < N) {
        starts[n] = s + pexcl;               // 4-int aligned (s%4==0, pexcl%4==0)
        ends[n]   = s + pexcl + deg;
        dis[n]    = dv;
    }
    cnt[t] = pexcl;                          // placement offsets (no atomics below)
    __syncthreads();

    // pass B: place rows (atomic-free; re-read binned in SAME order as pass A)
    for (int i0 = t * 4; i0 < mm; i0 += BIN_NODES * 4) {
        uint4 v = *(const uint4*)(binned + s + i0);
        srow[s + cnt[v.x >> 17] + arr[i0 + 0]] = v.x & 0x1FFFF;
        srow[s + cnt[v.y >> 17] + arr[i0 + 1]] = v.y & 0x1FFFF;
        srow[s + cnt[v.z >> 17] + arr[i0 + 2]] = v.z & 0x1FFFF;
        srow[s + cnt[v.w >> 17] + arr[i0 + 3]] = v.w & 0x1FFFF;
    }
    for (int i = mm + t; i < m; i += BIN_NODES) {
        unsigned v = binned[s + i];
        srow[s + cnt[v >> 17] + arr[i]] = v & 0x1FFFF;
    }

    // pass C: prescale this node's xw1 row by dis[n] (in place, coalesced 32B/thread)
    if (n < N) {
        uint4* p = (uint4*)(xw1 + (size_t)n * FH);
        uint4 va = p[0], vb = p[1];
        unsigned* u = &va.x;
        #pragma unroll
        for (int k = 0; k < 4; ++k)
            u[k] = (unsigned)f2bf(bflo(u[k]) * dv) | ((unsigned)f2bf(bfhi(u[k]) * dv) << 16);
        unsigned* w = &vb.x;
        #pragma unroll
        for (int k = 0; k < 4; ++k)
            w[k] = (unsigned)f2bf(bflo(w[k]) * dv) | ((unsigned)f2bf(bfhi(w[k]) * dv) << 16);
        p[0] = va; p[1] = vb;
    }
}

// ---- layer-1: 2 lanes/node, 16-deep gather pipeline, in-reg GEMM2 ----
__launch_bounds__(256)
__global__ void k_agg1(const int* __restrict__ starts, const int* __restrict__ ends,
                       const int* __restrict__ srow, const float* __restrict__ dis,
                       const unsigned short* __restrict__ xw1s, const float* __restrict__ W2,
                       const float* __restrict__ b1, unsigned short* __restrict__ xw2s, int N) {
    __shared__ float sw[FH * FO];
    __shared__ float sb[FH];
    int t = threadIdx.x;
    if (t < FH * FO) sw[t] = W2[t];
    if (t < FH) sb[t] = b1[t];
    __syncthreads();                       // before any early exit

    int n = blockIdx.x * 128 + (t >> 1);
    int h = t & 1;                         // feature half (8 bf16 = 1 uint4)
    if (n >= N) return;
    float dn = dis[n];
    int s = starts[n], e = ends[n];
    const uint4* xq = (const uint4*)xw1s;  // row r -> xq[2r + h]

    uint4 sp = xq[(size_t)n * 2 + h];      // self loop (prescaled)
    float acc[8];
    acc[0]=bflo(sp.x); acc[1]=bfhi(sp.x); acc[2]=bflo(sp.y); acc[3]=bfhi(sp.y);
    acc[4]=bflo(sp.z); acc[5]=bfhi(sp.z); acc[6]=bflo(sp.w); acc[7]=bfhi(sp.w);

    int i = s;
    for (; i + 16 <= e; i += 16) {         // 16 outstanding gathers
        int4 r0 = *(const int4*)(srow + i);
        int4 r1 = *(const int4*)(srow + i + 4);
        int4 r2 = *(const int4*)(srow + i + 8);
        int4 r3 = *(const int4*)(srow + i + 12);
        uint4 pk[16];
        pk[0]  = xq[(size_t)r0.x * 2 + h]; pk[1]  = xq[(size_t)r0.y * 2 + h];
        pk[2]  = xq[(size_t)r0.z * 2 + h]; pk[3]  = xq[(size_t)r0.w * 2 + h];
        pk[4]  = xq[(size_t)r1.x * 2 + h]; pk[5]  = xq[(size_t)r1.y * 2 + h];
        pk[6]  = xq[(size_t)r1.z * 2 + h]; pk[7]  = xq[(size_t)r1.w * 2 + h];
        pk[8]  = xq[(size_t)r2.x * 2 + h]; pk[9]  = xq[(size_t)r2.y * 2 + h];
        pk[10] = xq[(size_t)r2.z * 2 + h]; pk[11] = xq[(size_t)r2.w * 2 + h];
        pk[12] = xq[(size_t)r3.x * 2 + h]; pk[13] = xq[(size_t)r3.y * 2 + h];
        pk[14] = xq[(size_t)r3.z * 2 + h]; pk[15] = xq[(size_t)r3.w * 2 + h];
        #pragma unroll
        for (int j = 0; j < 16; ++j) {
            acc[0]+=bflo(pk[j].x); acc[1]+=bfhi(pk[j].x);
            acc[2]+=bflo(pk[j].y); acc[3]+=bfhi(pk[j].y);
            acc[4]+=bflo(pk[j].z); acc[5]+=bfhi(pk[j].z);
            acc[6]+=bflo(pk[j].w); acc[7]+=bfhi(pk[j].w);
        }
    }
    for (; i + 8 <= e; i += 8) {
        int4 ra = *(const int4*)(srow + i);
        int4 rb = *(const int4*)(srow + i + 4);
        uint4 pk[8];
        pk[0] = xq[(size_t)ra.x * 2 + h]; pk[1] = xq[(size_t)ra.y * 2 + h];
        pk[2] = xq[(size_t)ra.z * 2 + h]; pk[3] = xq[(size_t)ra.w * 2 + h];
        pk[4] = xq[(size_t)rb.x * 2 + h]; pk[5] = xq[(size_t)rb.y * 2 + h];
        pk[6] = xq[(size_t)rb.z * 2 + h]; pk[7] = xq[(size_t)rb.w * 2 + h];
        #pragma unroll
        for (int j = 0; j < 8; ++j) {
            acc[0]+=bflo(pk[j].x); acc[1]+=bfhi(pk[j].x);
            acc[2]+=bflo(pk[j].y); acc[3]+=bfhi(pk[j].y);
            acc[4]+=bflo(pk[j].z); acc[5]+=bfhi(pk[j].z);
            acc[6]+=bflo(pk[j].w); acc[7]+=bfhi(pk[j].w);
        }
    }
    for (; i < e; ++i) {
        uint4 p = xq[(size_t)srow[i] * 2 + h];
        acc[0]+=bflo(p.x); acc[1]+=bfhi(p.x);
        acc[2]+=bflo(p.y); acc[3]+=bfhi(p.y);
        acc[4]+=bflo(p.z); acc[5]+=bfhi(p.z);
        acc[6]+=bflo(p.w); acc[7]+=bfhi(p.w);
    }

    // relu + bias on own half (global k = h*8 + k)
    float hv[8];
    #pragma unroll
    for (int k = 0; k < 8; ++k) {
        float v = fmaf(dn, acc[k], sb[h * 8 + k]);
        hv[k] = v > 0.f ? v : 0.f;
    }
    // partial GEMM2 over own half, then partner-exchange
    float po[FO];
    #pragma unroll
    for (int o = 0; o < FO; ++o) {
        float a = 0.f;
        #pragma unroll
        for (int k = 0; k < 8; ++k) a = fmaf(hv[k], sw[(h * 8 + k) * FO + o], a);
        po[o] = a;
    }
    #pragma unroll
    for (int o = 0; o < FO; ++o) po[o] += __shfl_xor(po[o], 1, 64);
    // each lane writes its 4 outputs (prescaled by dn for layer 2)
    int o0 = h * 4;
    unsigned w0 = (unsigned)f2bf(po[o0 + 0] * dn) | ((unsigned)f2bf(po[o0 + 1] * dn) << 16);
    unsigned w1 = (unsigned)f2bf(po[o0 + 2] * dn) | ((unsigned)f2bf(po[o0 + 3] * dn) << 16);
    *(uint2*)(xw2s + (size_t)n * FO + o0) = make_uint2(w0, w1);
}

// ---- layer-2: 2 lanes/node, 16-deep gather pipeline + sigmoid ----
__launch_bounds__(256)
__global__ void k_agg2(const int* __restrict__ starts, const int* __restrict__ ends,
                       const int* __restrict__ srow, const float* __restrict__ dis,
                       const unsigned short* __restrict__ xw2s, const float* __restrict__ b2,
                       float* __restrict__ out, int N) {
    int t = threadIdx.x;
    int n = blockIdx.x * 128 + (t >> 1);
    int h = t & 1;                         // feature half (4 bf16 = 1 uint2)
    if (n >= N) return;
    float dn = dis[n];
    int s = starts[n], e = ends[n];
    const uint2* xq = (const uint2*)xw2s;  // row r -> xq[2r + h]

    uint2 sp = xq[(size_t)n * 2 + h];      // self loop (prescaled)
    float acc[4];
    acc[0]=bflo(sp.x); acc[1]=bfhi(sp.x); acc[2]=bflo(sp.y); acc[3]=bfhi(sp.y);

    int i = s;
    for (; i + 16 <= e; i += 16) {         // 16 outstanding gathers
        int4 r0 = *(const int4*)(srow + i);
        int4 r1 = *(const int4*)(srow + i + 4);
        int4 r2 = *(const int4*)(srow + i + 8);
        int4 r3 = *(const int4*)(srow + i + 12);
        uint2 pk[16];
        pk[0]  = xq[(size_t)r0.x * 2 + h]; pk[1]  = xq[(size_t)r0.y * 2 + h];
        pk[2]  = xq[(size_t)r0.z * 2 + h]; pk[3]  = xq[(size_t)r0.w * 2 + h];
        pk[4]  = xq[(size_t)r1.x * 2 + h]; pk[5]  = xq[(size_t)r1.y * 2 + h];
        pk[6]  = xq[(size_t)r1.z * 2 + h]; pk[7]  = xq[(size_t)r1.w * 2 + h];
        pk[8]  = xq[(size_t)r2.x * 2 + h]; pk[9]  = xq[(size_t)r2.y * 2 + h];
        pk[10] = xq[(size_t)r2.z * 2 + h]; pk[11] = xq[(size_t)r2.w * 2 + h];
        pk[12] = xq[(size_t)r3.x * 2 + h]; pk[13] = xq[(size_t)r3.y * 2 + h];
        pk[14] = xq[(size_t)r3.z * 2 + h]; pk[15] = xq[(size_t)r3.w * 2 + h];
        #pragma unroll
        for (int j = 0; j < 16; ++j) {
            acc[0]+=bflo(pk[j].x); acc[1]+=bfhi(pk[j].x);
            acc[2]+=bflo(pk[j].y); acc[3]+=bfhi(pk[j].y);
        }
    }
    for (; i + 8 <= e; i += 8) {
        int4 ra = *(const int4*)(srow + i);
        int4 rb = *(const int4*)(srow + i + 4);
        uint2 pk[8];
        pk[0] = xq[(size_t)ra.x * 2 + h]; pk[1] = xq[(size_t)ra.y * 2 + h];
        pk[2] = xq[(size_t)ra.z * 2 + h]; pk[3] = xq[(size_t)ra.w * 2 + h];
        pk[4] = xq[(size_t)rb.x * 2 + h]; pk[5] = xq[(size_t)rb.y * 2 + h];
        pk[6] = xq[(size_t)rb.z * 2 + h]; pk[7] = xq[(size_t)rb.w * 2 + h];
        #pragma unroll
        for (int j = 0; j < 8; ++j) {
            acc[0]+=bflo(pk[j].x); acc[1]+=bfhi(pk[j].x);
            acc[2]+=bflo(pk[j].y); acc[3]+=bfhi(pk[j].y);
        }
    }
    for (; i < e; ++i) {
        uint2 p = xq[(size_t)srow[i] * 2 + h];
        acc[0]+=bflo(p.x); acc[1]+=bfhi(p.x);
        acc[2]+=bflo(p.y); acc[3]+=bfhi(p.y);
    }

    int f0 = h * 4;
    float r[4];
    #pragma unroll
    for (int k = 0; k < 4; ++k) {
        float v = fmaf(dn, acc[k], b2[f0 + k]);
        r[k] = 1.f / (1.f + __expf(-v));
    }
    *(float4*)(out + (size_t)n * FO + f0) = make_float4(r[0], r[1], r[2], r[3]);
}

extern "C" void kernel_launch(void* const* d_in, const int* in_sizes, int n_in,
                              void* d_out, int out_size, void* d_ws, size_t ws_size,
                              hipStream_t stream) {
    const float* x  = (const float*)d_in[0];
    const int*   ei = (const int*)d_in[1];
    const float* W1 = (const float*)d_in[2];
    const float* b1 = (const float*)d_in[3];
    const float* W2 = (const float*)d_in[4];
    const float* b2 = (const float*)d_in[5];

    const int N = in_sizes[0] / FI;   // 100000
    const int E = in_sizes[1] / 2;    // 3200000
    const int* row = ei;
    const int* col = ei + E;
    const int nbins = (N + BIN_NODES - 1) >> BIN_SHIFT;   // 391

    const int nchunks = (E + SCHUNK - 1) / SCHUNK;        // 391
    const int ngemm   = (N + 255) / 256;                  // 391

    // workspace layout (4B units), no aliasing
    const size_t NP = 100352;
    const size_t BINSZ = (size_t)nbins * CAPB;            // 3,803,648
    float* base = (float*)d_ws;
    int*   starts    = (int*)base;                        // N
    int*   ends      = (int*)(base + NP);                 // N
    float* dis       = base + 2 * NP;                     // N
    int*   binCursor = (int*)(base + 3 * NP);             // nbins (pad 1024)
    unsigned int* binned = (unsigned int*)(base + 3 * NP + 1024);  // BINSZ
    int*   srow      = (int*)(base + 3 * NP + 1024 + BINSZ);       // BINSZ
    unsigned short* xw1s = (unsigned short*)(base + 3 * NP + 1024 + 2 * BINSZ);          // 16N bf16
    unsigned short* xw2s = (unsigned short*)(base + 3 * NP + 1024 + 2 * BINSZ + NP * 8); // 8N bf16
    float* out = (float*)d_out;

    size_t needed = (3 * NP + 1024 + 2 * BINSZ + NP * 12) * 4;
    if (ws_size < needed) return;

    hipMemsetAsync(binCursor, 0, (size_t)nbins * sizeof(int), stream);   // offset-form cursors
    k_scatter_gemm<<<nchunks + ngemm, SThreads, 0, stream>>>(row, col, binCursor, binned,
                                                             x, W1, xw1s, E, nchunks, N);
    k_refine      <<<nbins, BIN_NODES,          0, stream>>>(binCursor, binned, srow, starts, ends, dis, xw1s, N);
    k_agg1        <<<(2 * N + 255) / 256, 256,  0, stream>>>(starts, ends, srow, dis, xw1s, W2, b1, xw2s, N);
    k_agg2        <<<(2 * N + 255) / 256, 256,  0, stream>>>(starts, ends, srow, dis, xw2s, b2, out, N);
}

// Round 24
// 109.437 us; speedup vs baseline: 1.0904x; 1.0904x over previous
//
#include <hip/hip_runtime.h>
#include <math.h>

static constexpr int FI = 128;  // input features
static constexpr int FH = 16;   // hidden
static constexpr int FO = 8;    // classes

static constexpr int BIN_SHIFT = 8;        // 256 nodes per bin
static constexpr int BIN_NODES = 256;
static constexpr int MAX_BINS  = 512;      // supports N <= 131072 (row fits 17 bits)
static constexpr int CAPB      = 9728;     // per-bin capacity (mean 8192 +7sigma +768 pad)
static constexpr int SCHUNK    = 8192;     // edges per scatter chunk
static constexpr int SThreads  = 512;      // scatter/gemm block size (8 waves)

__device__ __forceinline__ unsigned short f2bf(float x) {
    unsigned u = __float_as_uint(x);
    u += 0x7FFFu + ((u >> 16) & 1u);       // round-to-nearest-even
    return (unsigned short)(u >> 16);
}
__device__ __forceinline__ float bflo(unsigned u) { return __uint_as_float(u << 16); }
__device__ __forceinline__ float bfhi(unsigned u) { return __uint_as_float(u & 0xFFFF0000u); }

// ---- fused: scatter chunks + unscaled gemm1, INTERLEAVED block mapping ----
struct SMemScatter {
    int lcnt[MAX_BINS];
    int lstart[MAX_BINS];
    int gbase[MAX_BINS];
    int wsum[8];
    unsigned int  staged[SCHUNK];          // 32 KB
    unsigned char sbin[SCHUNK];            // 8 KB
};
struct SMemGemm { float sw[FI * FH]; };    // 8 KB
union SMemU { SMemScatter s; SMemGemm g; };

__launch_bounds__(SThreads, 6)
__global__ void k_scatter_gemm(const int* __restrict__ row, const int* __restrict__ col,
                               int* __restrict__ binCursor, unsigned int* __restrict__ binned,
                               const float* __restrict__ x, const float* __restrict__ W1,
                               unsigned short* __restrict__ xw1, int E, int nchunks, int N) {
    __shared__ SMemU sm;
    int t = threadIdx.x;
    int i = (int)blockIdx.x;

    bool isScatter = ((i % 3) == 0) && ((i / 3) < nchunks);

    if (!isScatter) {
        // ---------------- gemm1 (unscaled): 128 nodes per block ----------------
        int nsc  = (i + 2) / 3; if (nsc > nchunks) nsc = nchunks;   // scatter blocks before i
        int tile = i - nsc;
        for (int k = t; k < FI * FH; k += SThreads) sm.g.sw[k] = W1[k];
        __syncthreads();
        int nl = t >> 2;            // 0..127 local node
        int f  = (t & 3) * 4;       // 0,4,8,12
        int n  = tile * 128 + nl;
        if (n >= N) return;
        const float4* xr = (const float4*)(x + (size_t)n * FI);
        float a0 = 0.f, a1 = 0.f, a2 = 0.f, a3 = 0.f;
        #pragma unroll 8
        for (int kq = 0; kq < FI / 4; ++kq) {
            float4 xv = xr[kq];
            float4 w0 = *(const float4*)&sm.g.sw[(kq * 4 + 0) * FH + f];
            float4 w1 = *(const float4*)&sm.g.sw[(kq * 4 + 1) * FH + f];
            float4 w2 = *(const float4*)&sm.g.sw[(kq * 4 + 2) * FH + f];
            float4 w3 = *(const float4*)&sm.g.sw[(kq * 4 + 3) * FH + f];
            a0 = fmaf(xv.x, w0.x, a0); a1 = fmaf(xv.x, w0.y, a1);
            a2 = fmaf(xv.x, w0.z, a2); a3 = fmaf(xv.x, w0.w, a3);
            a0 = fmaf(xv.y, w1.x, a0); a1 = fmaf(xv.y, w1.y, a1);
            a2 = fmaf(xv.y, w1.z, a2); a3 = fmaf(xv.y, w1.w, a3);
            a0 = fmaf(xv.z, w2.x, a0); a1 = fmaf(xv.z, w2.y, a1);
            a2 = fmaf(xv.z, w2.z, a2); a3 = fmaf(xv.z, w2.w, a3);
            a0 = fmaf(xv.w, w3.x, a0); a1 = fmaf(xv.w, w3.y, a1);
            a2 = fmaf(xv.w, w3.z, a2); a3 = fmaf(xv.w, w3.w, a3);
        }
        unsigned p0 = (unsigned)f2bf(a0) | ((unsigned)f2bf(a1) << 16);
        unsigned p1 = (unsigned)f2bf(a2) | ((unsigned)f2bf(a3) << 16);
        *(uint2*)(xw1 + (size_t)n * FH + f) = make_uint2(p0, p1);
        return;
    }

    // ---------------- scatter chunk ----------------
    int chunk = i / 3;
    int base = chunk * SCHUNK;
    int end  = base + SCHUNK; if (end > E) end = E;
    int m = end - base;
    sm.s.lcnt[t] = 0;                       // SThreads == MAX_BINS == 512
    __syncthreads();

    // pass 1: histogram; col AND arrival index staged in registers
    int nv = m >> 2;
    const int4* c4 = (const int4*)(col + base);
    int4 creg[4];
    unsigned short a16[16];
    #pragma unroll
    for (int j = 0; j < 4; ++j) {
        int k = t + j * SThreads;
        if (k < nv) {
            creg[j] = c4[k];
            a16[j*4+0] = (unsigned short)atomicAdd(&sm.s.lcnt[creg[j].x >> BIN_SHIFT], 1);
            a16[j*4+1] = (unsigned short)atomicAdd(&sm.s.lcnt[creg[j].y >> BIN_SHIFT], 1);
            a16[j*4+2] = (unsigned short)atomicAdd(&sm.s.lcnt[creg[j].z >> BIN_SHIFT], 1);
            a16[j*4+3] = (unsigned short)atomicAdd(&sm.s.lcnt[creg[j].w >> BIN_SHIFT], 1);
        }
    }
    int tailIdx = base + (nv << 2) + t;     // at most 3 tail edges total
    int tailCol = 0, tailA = -1;
    if (tailIdx < end) {
        tailCol = col[tailIdx];
        tailA = atomicAdd(&sm.s.lcnt[tailCol >> BIN_SHIFT], 1);
    }
    __syncthreads();

    // wave-shuffle scan over 512 bins (8 waves)
    int v = sm.s.lcnt[t];
    int inc = v;
    #pragma unroll
    for (int d = 1; d < 64; d <<= 1) {
        int u = __shfl_up(inc, d, 64);
        if ((t & 63) >= d) inc += u;
    }
    if ((t & 63) == 63) sm.s.wsum[t >> 6] = inc;
    __syncthreads();
    if (t < 8) {
        int w = sm.s.wsum[t];
        #pragma unroll
        for (int d = 1; d < 8; d <<= 1) {
            int u = __shfl_up(w, d, 8);
            if (t >= d) w += u;
        }
        sm.s.wsum[t] = w;
    }
    __syncthreads();
    {
        int waveoff = (t >= 64) ? sm.s.wsum[(t >> 6) - 1] : 0;
        sm.s.lstart[t] = waveoff + inc - v;
        sm.s.gbase[t]  = v ? atomicAdd(&binCursor[t], v) : 0;   // offset within bin region
    }
    __syncthreads();

    // pass 2: place into LDS staging (atomic-free: lstart[bin] + arrival)
    const int4* r4 = (const int4*)(row + base);
    #pragma unroll
    for (int j = 0; j < 4; ++j) {
        int k = t + j * SThreads;
        if (k < nv) {
            int4 r = r4[k];
            int cc[4] = {creg[j].x, creg[j].y, creg[j].z, creg[j].w};
            int rr[4] = {r.x, r.y, r.z, r.w};
            #pragma unroll
            for (int jj = 0; jj < 4; ++jj) {
                int b = cc[jj] >> BIN_SHIFT;
                int pos = sm.s.lstart[b] + a16[j*4+jj];
                sm.s.staged[pos] = (unsigned)rr[jj] | ((unsigned)(cc[jj] & (BIN_NODES - 1)) << 17)
                                 | ((unsigned)(b >> 8) << 25);
                sm.s.sbin[pos] = (unsigned char)b;
            }
        }
    }
    if (tailA >= 0) {
        int b = tailCol >> BIN_SHIFT;
        int pos = sm.s.lstart[b] + tailA;
        sm.s.staged[pos] = (unsigned)row[tailIdx] | ((unsigned)(tailCol & (BIN_NODES - 1)) << 17)
                         | ((unsigned)(b >> 8) << 25);
        sm.s.sbin[pos] = (unsigned char)b;
    }
    __syncthreads();

    // pass 3: coalesced flush (consecutive i in a run -> consecutive global addrs)
    for (int k = t; k < m; k += SThreads) {
        unsigned sv = sm.s.staged[k];
        int b = (int)sm.s.sbin[k] | (int)((sv >> 25) & 1u) << 8;
        int off = sm.s.gbase[b] + (k - sm.s.lstart[b]);
        if (off < CAPB) binned[b * CAPB + off] = sv & 0x1FFFFFFu;
    }
}

// ---- per-bin CSR build: arrival-idx hist -> PADDED scan (4-aligned runs) ----
__launch_bounds__(BIN_NODES)
__global__ void k_refine(const int* __restrict__ binCursor, const unsigned int* __restrict__ binned,
                         int* __restrict__ srow, int* __restrict__ starts, int* __restrict__ ends,
                         float* __restrict__ dis, unsigned short* __restrict__ xw1, int N) {
    __shared__ unsigned char arr[CAPB];      // 9.5 KB arrival index (deg < 256)
    __shared__ int cnt[BIN_NODES];           // histogram -> padded exclusive offsets
    __shared__ int wsum[4];
    int t = threadIdx.x;
    int b = blockIdx.x;
    int s = b * CAPB;
    int m = binCursor[b];                    // count of edges in bin
    if (m > CAPB - 768) m = CAPB - 768;      // leave room for per-node pad
    cnt[t] = 0;
    __syncthreads();

    // pass A: histogram with arrival index (single atomic per edge)
    int mm = m & ~3;
    for (int i0 = t * 4; i0 < mm; i0 += BIN_NODES * 4) {
        uint4 v = *(const uint4*)(binned + s + i0);
        arr[i0 + 0] = (unsigned char)atomicAdd(&cnt[v.x >> 17], 1);
        arr[i0 + 1] = (unsigned char)atomicAdd(&cnt[v.y >> 17], 1);
        arr[i0 + 2] = (unsigned char)atomicAdd(&cnt[v.z >> 17], 1);
        arr[i0 + 3] = (unsigned char)atomicAdd(&cnt[v.w >> 17], 1);
    }
    for (int i = mm + t; i < m; i += BIN_NODES)
        arr[i] = (unsigned char)atomicAdd(&cnt[binned[s + i] >> 17], 1);
    __syncthreads();

    // wave-shuffle inclusive scan of 256 PADDED degrees (runs 4-int aligned)
    int deg  = cnt[t];
    int pdeg = (deg + 3) & ~3;
    int inc = pdeg;
    #pragma unroll
    for (int d = 1; d < 64; d <<= 1) {
        int u = __shfl_up(inc, d, 64);
        if ((t & 63) >= d) inc += u;
    }
    if ((t & 63) == 63) wsum[t >> 6] = inc;
    __syncthreads();
    if (t < 4) {
        int w = wsum[t];
        #pragma unroll
        for (int d = 1; d < 4; d <<= 1) {
            int u = __shfl_up(w, d, 4);
            if (t >= d) w += u;
        }
        wsum[t] = w;
    }
    __syncthreads();
    int waveoff = (t >= 64) ? wsum[(t >> 6) - 1] : 0;
    int pexcl = waveoff + inc - pdeg;

    int n = b * BIN_NODES + t;
    float dv = rsqrtf((float)(deg + 1));     // +1 self loop
    if (n < N) {
        starts[n] = s + pexcl;               // 4-int aligned (s%4==0, pexcl%4==0)
        ends[n]   = s + pexcl + deg;
        dis[n]    = dv;
    }
    cnt[t] = pexcl;                          // placement offsets (no atomics below)
    __syncthreads();

    // pass B: place rows (atomic-free; re-read binned in SAME order as pass A)
    for (int i0 = t * 4; i0 < mm; i0 += BIN_NODES * 4) {
        uint4 v = *(const uint4*)(binned + s + i0);
        srow[s + cnt[v.x >> 17] + arr[i0 + 0]] = v.x & 0x1FFFF;
        srow[s + cnt[v.y >> 17] + arr[i0 + 1]] = v.y & 0x1FFFF;
        srow[s + cnt[v.z >> 17] + arr[i0 + 2]] = v.z & 0x1FFFF;
        srow[s + cnt[v.w >> 17] + arr[i0 + 3]] = v.w & 0x1FFFF;
    }
    for (int i = mm + t; i < m; i += BIN_NODES) {
        unsigned v = binned[s + i];
        srow[s + cnt[v >> 17] + arr[i]] = v & 0x1FFFF;
    }

    // pass C: prescale this node's xw1 row by dis[n] (in place, coalesced 32B/thread)
    if (n < N) {
        uint4* p = (uint4*)(xw1 + (size_t)n * FH);
        uint4 va = p[0], vb = p[1];
        unsigned* u = &va.x;
        #pragma unroll
        for (int k = 0; k < 4; ++k)
            u[k] = (unsigned)f2bf(bflo(u[k]) * dv) | ((unsigned)f2bf(bfhi(u[k]) * dv) << 16);
        unsigned* w = &vb.x;
        #pragma unroll
        for (int k = 0; k < 4; ++k)
            w[k] = (unsigned)f2bf(bflo(w[k]) * dv) | ((unsigned)f2bf(bfhi(w[k]) * dv) << 16);
        p[0] = va; p[1] = vb;
    }
}

// ---- layer-1: 2 lanes/node, 16-deep gather pipeline, in-reg GEMM2 ----
__launch_bounds__(256)
__global__ void k_agg1(const int* __restrict__ starts, const int* __restrict__ ends,
                       const int* __restrict__ srow, const float* __restrict__ dis,
                       const unsigned short* __restrict__ xw1s, const float* __restrict__ W2,
                       const float* __restrict__ b1, unsigned short* __restrict__ xw2s, int N) {
    __shared__ float sw[FH * FO];
    __shared__ float sb[FH];
    int t = threadIdx.x;
    if (t < FH * FO) sw[t] = W2[t];
    if (t < FH) sb[t] = b1[t];
    __syncthreads();                       // before any early exit

    int n = blockIdx.x * 128 + (t >> 1);
    int h = t & 1;                         // feature half (8 bf16 = 1 uint4)
    if (n >= N) return;
    float dn = dis[n];
    int s = starts[n], e = ends[n];
    const uint4* xq = (const uint4*)xw1s;  // row r -> xq[2r + h]

    uint4 sp = xq[(size_t)n * 2 + h];      // self loop (prescaled)
    float acc[8];
    acc[0]=bflo(sp.x); acc[1]=bfhi(sp.x); acc[2]=bflo(sp.y); acc[3]=bfhi(sp.y);
    acc[4]=bflo(sp.z); acc[5]=bfhi(sp.z); acc[6]=bflo(sp.w); acc[7]=bfhi(sp.w);

    int i = s;
    for (; i + 16 <= e; i += 16) {         // 16 outstanding gathers
        int4 r0 = *(const int4*)(srow + i);
        int4 r1 = *(const int4*)(srow + i + 4);
        int4 r2 = *(const int4*)(srow + i + 8);
        int4 r3 = *(const int4*)(srow + i + 12);
        uint4 pk[16];
        pk[0]  = xq[(size_t)r0.x * 2 + h]; pk[1]  = xq[(size_t)r0.y * 2 + h];
        pk[2]  = xq[(size_t)r0.z * 2 + h]; pk[3]  = xq[(size_t)r0.w * 2 + h];
        pk[4]  = xq[(size_t)r1.x * 2 + h]; pk[5]  = xq[(size_t)r1.y * 2 + h];
        pk[6]  = xq[(size_t)r1.z * 2 + h]; pk[7]  = xq[(size_t)r1.w * 2 + h];
        pk[8]  = xq[(size_t)r2.x * 2 + h]; pk[9]  = xq[(size_t)r2.y * 2 + h];
        pk[10] = xq[(size_t)r2.z * 2 + h]; pk[11] = xq[(size_t)r2.w * 2 + h];
        pk[12] = xq[(size_t)r3.x * 2 + h]; pk[13] = xq[(size_t)r3.y * 2 + h];
        pk[14] = xq[(size_t)r3.z * 2 + h]; pk[15] = xq[(size_t)r3.w * 2 + h];
        #pragma unroll
        for (int j = 0; j < 16; ++j) {
            acc[0]+=bflo(pk[j].x); acc[1]+=bfhi(pk[j].x);
            acc[2]+=bflo(pk[j].y); acc[3]+=bfhi(pk[j].y);
            acc[4]+=bflo(pk[j].z); acc[5]+=bfhi(pk[j].z);
            acc[6]+=bflo(pk[j].w); acc[7]+=bfhi(pk[j].w);
        }
    }
    for (; i + 8 <= e; i += 8) {
        int4 ra = *(const int4*)(srow + i);
        int4 rb = *(const int4*)(srow + i + 4);
        uint4 pk[8];
        pk[0] = xq[(size_t)ra.x * 2 + h]; pk[1] = xq[(size_t)ra.y * 2 + h];
        pk[2] = xq[(size_t)ra.z * 2 + h]; pk[3] = xq[(size_t)ra.w * 2 + h];
        pk[4] = xq[(size_t)rb.x * 2 + h]; pk[5] = xq[(size_t)rb.y * 2 + h];
        pk[6] = xq[(size_t)rb.z * 2 + h]; pk[7] = xq[(size_t)rb.w * 2 + h];
        #pragma unroll
        for (int j = 0; j < 8; ++j) {
            acc[0]+=bflo(pk[j].x); acc[1]+=bfhi(pk[j].x);
            acc[2]+=bflo(pk[j].y); acc[3]+=bfhi(pk[j].y);
            acc[4]+=bflo(pk[j].z); acc[5]+=bfhi(pk[j].z);
            acc[6]+=bflo(pk[j].w); acc[7]+=bfhi(pk[j].w);
        }
    }
    for (; i < e; ++i) {
        uint4 p = xq[(size_t)srow[i] * 2 + h];
        acc[0]+=bflo(p.x); acc[1]+=bfhi(p.x);
        acc[2]+=bflo(p.y); acc[3]+=bfhi(p.y);
        acc[4]+=bflo(p.z); acc[5]+=bfhi(p.z);
        acc[6]+=bflo(p.w); acc[7]+=bfhi(p.w);
    }

    // relu + bias on own half (global k = h*8 + k)
    float hv[8];
    #pragma unroll
    for (int k = 0; k < 8; ++k) {
        float v = fmaf(dn, acc[k], sb[h * 8 + k]);
        hv[k] = v > 0.f ? v : 0.f;
    }
    // partial GEMM2 over own half, then partner-exchange
    float po[FO];
    #pragma unroll
    for (int o = 0; o < FO; ++o) {
        float a = 0.f;
        #pragma unroll
        for (int k = 0; k < 8; ++k) a = fmaf(hv[k], sw[(h * 8 + k) * FO + o], a);
        po[o] = a;
    }
    #pragma unroll
    for (int o = 0; o < FO; ++o) po[o] += __shfl_xor(po[o], 1, 64);
    // each lane writes its 4 outputs (prescaled by dn for layer 2)
    int o0 = h * 4;
    unsigned w0 = (unsigned)f2bf(po[o0 + 0] * dn) | ((unsigned)f2bf(po[o0 + 1] * dn) << 16);
    unsigned w1 = (unsigned)f2bf(po[o0 + 2] * dn) | ((unsigned)f2bf(po[o0 + 3] * dn) << 16);
    *(uint2*)(xw2s + (size_t)n * FO + o0) = make_uint2(w0, w1);
}

// ---- layer-2: 2 lanes/node, 16-deep gather pipeline + sigmoid ----
__launch_bounds__(256)
__global__ void k_agg2(const int* __restrict__ starts, const int* __restrict__ ends,
                       const int* __restrict__ srow, const float* __restrict__ dis,
                       const unsigned short* __restrict__ xw2s, const float* __restrict__ b2,
                       float* __restrict__ out, int N) {
    int t = threadIdx.x;
    int n = blockIdx.x * 128 + (t >> 1);
    int h = t & 1;                         // feature half (4 bf16 = 1 uint2)
    if (n >= N) return;
    float dn = dis[n];
    int s = starts[n], e = ends[n];
    const uint2* xq = (const uint2*)xw2s;  // row r -> xq[2r + h]

    uint2 sp = xq[(size_t)n * 2 + h];      // self loop (prescaled)
    float acc[4];
    acc[0]=bflo(sp.x); acc[1]=bfhi(sp.x); acc[2]=bflo(sp.y); acc[3]=bfhi(sp.y);

    int i = s;
    for (; i + 16 <= e; i += 16) {         // 16 outstanding gathers
        int4 r0 = *(const int4*)(srow + i);
        int4 r1 = *(const int4*)(srow + i + 4);
        int4 r2 = *(const int4*)(srow + i + 8);
        int4 r3 = *(const int4*)(srow + i + 12);
        uint2 pk[16];
        pk[0]  = xq[(size_t)r0.x * 2 + h]; pk[1]  = xq[(size_t)r0.y * 2 + h];
        pk[2]  = xq[(size_t)r0.z * 2 + h]; pk[3]  = xq[(size_t)r0.w * 2 + h];
        pk[4]  = xq[(size_t)r1.x * 2 + h]; pk[5]  = xq[(size_t)r1.y * 2 + h];
        pk[6]  = xq[(size_t)r1.z * 2 + h]; pk[7]  = xq[(size_t)r1.w * 2 + h];
        pk[8]  = xq[(size_t)r2.x * 2 + h]; pk[9]  = xq[(size_t)r2.y * 2 + h];
        pk[10] = xq[(size_t)r2.z * 2 + h]; pk[11] = xq[(size_t)r2.w * 2 + h];
        pk[12] = xq[(size_t)r3.x * 2 + h]; pk[13] = xq[(size_t)r3.y * 2 + h];
        pk[14] = xq[(size_t)r3.z * 2 + h]; pk[15] = xq[(size_t)r3.w * 2 + h];
        #pragma unroll
        for (int j = 0; j < 16; ++j) {
            acc[0]+=bflo(pk[j].x); acc[1]+=bfhi(pk[j].x);
            acc[2]+=bflo(pk[j].y); acc[3]+=bfhi(pk[j].y);
        }
    }
    for (; i + 8 <= e; i += 8) {
        int4 ra = *(const int4*)(srow + i);
        int4 rb = *(const int4*)(srow + i + 4);
        uint2 pk[8];
        pk[0] = xq[(size_t)ra.x * 2 + h]; pk[1] = xq[(size_t)ra.y * 2 + h];
        pk[2] = xq[(size_t)ra.z * 2 + h]; pk[3] = xq[(size_t)ra.w * 2 + h];
        pk[4] = xq[(size_t)rb.x * 2 + h]; pk[5] = xq[(size_t)rb.y * 2 + h];
        pk[6] = xq[(size_t)rb.z * 2 + h]; pk[7] = xq[(size_t)rb.w * 2 + h];
        #pragma unroll
        for (int j = 0; j < 8; ++j) {
            acc[0]+=bflo(pk[j].x); acc[1]+=bfhi(pk[j].x);
            acc[2]+=bflo(pk[j].y); acc[3]+=bfhi(pk[j].y);
        }
    }
    for (; i < e; ++i) {
        uint2 p = xq[(size_t)srow[i] * 2 + h];
        acc[0]+=bflo(p.x); acc[1]+=bfhi(p.x);
        acc[2]+=bflo(p.y); acc[3]+=bfhi(p.y);
    }

    int f0 = h * 4;
    float r[4];
    #pragma unroll
    for (int k = 0; k < 4; ++k) {
        float v = fmaf(dn, acc[k], b2[f0 + k]);
        r[k] = 1.f / (1.f + __expf(-v));
    }
    *(float4*)(out + (size_t)n * FO + f0) = make_float4(r[0], r[1], r[2], r[3]);
}

extern "C" void kernel_launch(void* const* d_in, const int* in_sizes, int n_in,
                              void* d_out, int out_size, void* d_ws, size_t ws_size,
                              hipStream_t stream) {
    const float* x  = (const float*)d_in[0];
    const int*   ei = (const int*)d_in[1];
    const float* W1 = (const float*)d_in[2];
    const float* b1 = (const float*)d_in[3];
    const float* W2 = (const float*)d_in[4];
    const float* b2 = (const float*)d_in[5];

    const int N = in_sizes[0] / FI;   // 100000
    const int E = in_sizes[1] / 2;    // 3200000
    const int* row = ei;
    const int* col = ei + E;
    const int nbins = (N + BIN_NODES - 1) >> BIN_SHIFT;   // 391

    const int nchunks = (E + SCHUNK - 1) / SCHUNK;        // 391
    const int ngemm   = (N + 127) / 128;                  // 782

    // workspace layout (4B units), no aliasing
    const size_t NP = 100352;
    const size_t BINSZ = (size_t)nbins * CAPB;            // 3,803,648
    float* base = (float*)d_ws;
    int*   starts    = (int*)base;                        // N
    int*   ends      = (int*)(base + NP);                 // N
    float* dis       = base + 2 * NP;                     // N
    int*   binCursor = (int*)(base + 3 * NP);             // nbins (pad 1024)
    unsigned int* binned = (unsigned int*)(base + 3 * NP + 1024);  // BINSZ
    int*   srow      = (int*)(base + 3 * NP + 1024 + BINSZ);       // BINSZ
    unsigned short* xw1s = (unsigned short*)(base + 3 * NP + 1024 + 2 * BINSZ);          // 16N bf16
    unsigned short* xw2s = (unsigned short*)(base + 3 * NP + 1024 + 2 * BINSZ + NP * 8); // 8N bf16
    float* out = (float*)d_out;

    size_t needed = (3 * NP + 1024 + 2 * BINSZ + NP * 12) * 4;
    if (ws_size < needed) return;

    hipMemsetAsync(binCursor, 0, (size_t)nbins * sizeof(int), stream);   // offset-form cursors
    k_scatter_gemm<<<nchunks + ngemm, SThreads, 0, stream>>>(row, col, binCursor, binned,
                                                             x, W1, xw1s, E, nchunks, N);
    k_refine      <<<nbins, BIN_NODES,          0, stream>>>(binCursor, binned, srow, starts, ends, dis, xw1s, N);
    k_agg1        <<<(2 * N + 255) / 256, 256,  0, stream>>>(starts, ends, srow, dis, xw1s, W2, b1, xw2s, N);
    k_agg2        <<<(2 * N + 255) / 256, 256,  0, stream>>>(starts, ends, srow, dis, xw2s, b2, out, N);
}